// Round 6
// baseline (167.717 us; speedup 1.0000x reference)
//
#include <hip/hip_runtime.h>

// Batched scalar neural-ODE, RK4, 99 steps, tiny 2->4->1 LeakyReLU MLP.
// R6 = R5 with the compile fix: __builtin_nontemporal_store requires a
// native clang vector type, not HIP's float4 class -> use ext_vector_type(4).
//
// Structure: R1's winning config (1 elem/thread, 256-thread blocks, 2048
// waves = 2 waves/SIMD, direct per-row float4 stores) + two deltas:
//   (a) algebraic fold of the MLP's linear part (59 -> 51 VALU/step):
//       leaky(h) = 0.505*h + 0.495*|h|
//       dyn(s) = fma(s, P, Q) + sum_i (0.495 w_i)*|A_i*s + C_i|
//       P = sum_i (0.505 w_i) A_i (uniform); Q = b2 + sum_i (0.505 w_i) C_i,
//       C_i = u*W1[1][i] + b1[i] (per-thread). |h| = free VOP3 abs modifier.
//   (b) nontemporal output stores: 52 MB streams through L2 (4 MiB/XCD)
//       exactly once — evict-first hint avoids thrashing.
// Evidence from R1/R2/R4 A/B: LDS-coalesced stores regressed (occupancy),
// 2 elem/thread at 1 wave/SIMD regressed (no TLP to hide store stalls) ->
// 2 waves/SIMD + direct stores is the right config; only shrink the
// instruction stream.

#define NSTEP 100
#define BLK 256

typedef float floatx4 __attribute__((ext_vector_type(4)));

__global__ __launch_bounds__(BLK, 2) void rk4_net_kernel(
    const float* __restrict__ x, const float* __restrict__ u,
    const float* __restrict__ W1, const float* __restrict__ b1,
    const float* __restrict__ W2, const float* __restrict__ b2,
    float* __restrict__ out, int B)
{
    const int b = blockIdx.x * BLK + threadIdx.x;
    if (b >= B) return;

    // Uniform weights (W1 row-major (2,4): row 0 multiplies s, row 1 multiplies u)
    const float A0 = W1[0], A1 = W1[1], A2 = W1[2], A3 = W1[3];
    const float U0 = W1[4], U1 = W1[5], U2 = W1[6], U3 = W1[7];
    const float w0 = W2[0], w1 = W2[1], w2 = W2[2], w3 = W2[3];
    const float bias2 = b2[0];

    const float al = 0.505f, be = 0.495f;
    const float wa0 = al * w0, wa1 = al * w1, wa2 = al * w2, wa3 = al * w3;
    const float wb0 = be * w0, wb1 = be * w1, wb2 = be * w2, wb3 = be * w3;
    // Linear fold: P = sum wa_i * A_i (uniform)
    float P = wa0 * A0;
    P = fmaf(wa1, A1, P);
    P = fmaf(wa2, A2, P);
    P = fmaf(wa3, A3, P);

    const float uu = u[b];
    float s = x[b];

    // Per-thread constants: C_i = u*W1[1][i] + b1[i];  Q = b2 + sum wa_i C_i
    const float C0 = fmaf(uu, U0, b1[0]);
    const float C1 = fmaf(uu, U1, b1[1]);
    const float C2 = fmaf(uu, U2, b1[2]);
    const float C3 = fmaf(uu, U3, b1[3]);
    float Q = fmaf(wa0, C0, bias2);
    Q = fmaf(wa1, C1, Q);
    Q = fmaf(wa2, C2, Q);
    Q = fmaf(wa3, C3, Q);

    // dyn = 11 VALU, two parallel chains + linear term
    auto dyn = [&](float sv) -> float {
        float h0 = fmaf(sv, A0, C0);
        float h1 = fmaf(sv, A1, C1);
        float h2 = fmaf(sv, A2, C2);
        float h3 = fmaf(sv, A3, C3);
        float t0 = __builtin_fabsf(h0) * wb0;
        float t1 = __builtin_fabsf(h1) * wb1;
        t0 = fmaf(__builtin_fabsf(h2), wb2, t0);
        t1 = fmaf(__builtin_fabsf(h3), wb3, t1);
        float lin = fmaf(sv, P, Q);
        return lin + (t0 + t1);
    };

    auto step = [&](float sv) -> float {
        float k1 = dyn(sv);
        float k2 = dyn(fmaf(0.5f, k1, sv));
        float k3 = dyn(fmaf(0.5f, k2, sv));
        float k4 = dyn(sv + k3);
        float sum = fmaf(2.0f, k2, k1);
        sum = fmaf(2.0f, k3, sum);
        sum += k4;
        return fmaf(0.16666667f, sum, sv);  // DT/6
    };

    // Output row: out[b*100 .. b*100+99]; base (b*400B) is 16B aligned.
    floatx4* o4 = (floatx4*)(out + (size_t)b * NSTEP);

    floatx4 v;
    v.x = s;                 // t = 0 is the initial state
    s = step(s); v.y = s;
    s = step(s); v.z = s;
    s = step(s); v.w = s;
    __builtin_nontemporal_store(v, &o4[0]);

#pragma unroll 1
    for (int c = 1; c < 25; ++c) {
        s = step(s); v.x = s;
        s = step(s); v.y = s;
        s = step(s); v.z = s;
        s = step(s); v.w = s;
        __builtin_nontemporal_store(v, &o4[c]);
    }
}

extern "C" void kernel_launch(void* const* d_in, const int* in_sizes, int n_in,
                              void* d_out, int out_size, void* d_ws, size_t ws_size,
                              hipStream_t stream) {
    const float* x  = (const float*)d_in[0];
    const float* u  = (const float*)d_in[1];
    const float* W1 = (const float*)d_in[2];
    const float* b1 = (const float*)d_in[3];
    const float* W2 = (const float*)d_in[4];
    const float* b2 = (const float*)d_in[5];
    float* out = (float*)d_out;

    const int B = in_sizes[0];
    const int grid = (B + BLK - 1) / BLK;   // 512 blocks -> 2048 waves
    hipLaunchKernelGGL(rk4_net_kernel, dim3(grid), dim3(BLK), 0, stream,
                       x, u, W1, b1, W2, b2, out, B);
}